// Round 6
// baseline (526.909 us; speedup 1.0000x reference)
//
#include <hip/hip_runtime.h>
#include <hip/hip_bf16.h>
#include <stdint.h>

#define NR 8192
#define FD 512
#define BM 64     // k_attn rows per band
#define BKC 128   // k_attn j per chunk

typedef __attribute__((ext_vector_type(8))) short s8v;   // 8 bf16 (4 VGPRs) - MFMA A/B frag
typedef __attribute__((ext_vector_type(4))) float f32x4; // MFMA C/D frag

static __device__ __forceinline__ short bf16_rtne(float x) {
    union { float f; uint32_t u; } v; v.f = x;
    uint32_t r = (v.u + 0x7FFFu + ((v.u >> 16) & 1u)) >> 16;
    return (short)r;
}
static __device__ __forceinline__ float bf16_to_f32(short s) {
    union { uint32_t u; float f; } v; v.u = ((uint32_t)(uint16_t)s) << 16;
    return v.f;
}

// ---------------- K0a: fp32 -> bf16 convert (inp) ----------------
__global__ void k_convert(const float* __restrict__ in, short* __restrict__ out) {
    int i = blockIdx.x * blockDim.x + threadIdx.x;   // one float4 per thread
    float4 v = ((const float4*)in)[i];
    short4 s;
    s.x = bf16_rtne(v.x); s.y = bf16_rtne(v.y);
    s.z = bf16_rtne(v.z); s.w = bf16_rtne(v.w);
    ((short4*)out)[i] = s;
}

// ---------------- K0b: W1 [k][n] -> W1T bf16 [n][k] ----------------
__global__ void k_w1t(const float* __restrict__ W1, short* __restrict__ W1T) {
    int i = blockIdx.x * 256 + threadIdx.x;  // 512*512
    int k = i & 511, n = i >> 9;
    W1T[(size_t)n * 512 + k] = bf16_rtne(W1[(size_t)k * 512 + n]);
}

// ---------------- K1: h = inp @ W1 + b1 ; writes h AND ht2 ----------------
// ht2 layout: [jt=row/32][col][row%32] bf16 (tile-contiguous for k_attn B-frags)
__launch_bounds__(256)
__global__ void k_gemm_h(const short* __restrict__ A,   // inp bf16 [8192][512]
                         const short* __restrict__ BT,  // W1T bf16 [512][512]
                         const float* __restrict__ b1,
                         short* __restrict__ H,         // bf16 [8192][512]
                         short* __restrict__ HT2)       // bf16 [256][512][32]
{
    const int lane = threadIdx.x & 63;
    const int wn   = threadIdx.x >> 6;     // 0..3
    const int m    = lane & 15;
    const int q    = lane >> 4;
    const int r0   = blockIdx.x * 32;
    const int c0   = blockIdx.y * 128 + wn * 32;

    f32x4 acc[2][2] = {};
#pragma unroll 1
    for (int k0 = 0; k0 < 512; k0 += 32) {
        s8v a[2], b[2];
#pragma unroll
        for (int rt = 0; rt < 2; ++rt)
            a[rt] = *(const s8v*)(A + (size_t)(r0 + rt * 16 + m) * 512 + k0 + q * 8);
#pragma unroll
        for (int nt = 0; nt < 2; ++nt)
            b[nt] = *(const s8v*)(BT + (size_t)(c0 + nt * 16 + m) * 512 + k0 + q * 8);
#pragma unroll
        for (int rt = 0; rt < 2; ++rt)
#pragma unroll
            for (int nt = 0; nt < 2; ++nt)
                acc[rt][nt] = __builtin_amdgcn_mfma_f32_16x16x32_bf16(a[rt], b[nt], acc[rt][nt], 0, 0, 0);
    }
    float b1v[2];
#pragma unroll
    for (int nt = 0; nt < 2; ++nt) b1v[nt] = b1[c0 + nt * 16 + m];

#pragma unroll
    for (int rt = 0; rt < 2; ++rt)
#pragma unroll
        for (int nt = 0; nt < 2; ++nt) {
            int col = c0 + nt * 16 + m;
            short4 hp;
#pragma unroll
            for (int r = 0; r < 4; ++r) {
                int row = r0 + rt * 16 + q * 4 + r;
                short hv = bf16_rtne(acc[rt][nt][r] + b1v[nt]);
                H[(size_t)row * 512 + col] = hv;
                ((short*)&hp)[r] = hv;
            }
            *(short4*)(HT2 + (size_t)blockIdx.x * (512 * 32) + (size_t)col * 32 + rt * 16 + q * 4) = hp;
        }
}

// ---------------- K3: f1 = h@a1, f2s = h@a2 + b2 ----------------
__global__ void k_f1f2(const short* __restrict__ H, const float* __restrict__ a1,
                       const float* __restrict__ a2, const float* __restrict__ b2,
                       float* __restrict__ f1, float* __restrict__ f2s)
{
    const int lane = threadIdx.x & 63;
    const int row  = blockIdx.x * 4 + (threadIdx.x >> 6);
    s8v hv = *(const s8v*)(H + (size_t)row * 512 + lane * 8);
    float4 a1l = ((const float4*)(a1 + lane * 8))[0];
    float4 a1h = ((const float4*)(a1 + lane * 8))[1];
    float4 a2l = ((const float4*)(a2 + lane * 8))[0];
    float4 a2h = ((const float4*)(a2 + lane * 8))[1];
    float hf[8];
#pragma unroll
    for (int i = 0; i < 8; ++i) hf[i] = bf16_to_f32(hv[i]);
    float s1 = hf[0] * a1l.x + hf[1] * a1l.y + hf[2] * a1l.z + hf[3] * a1l.w
             + hf[4] * a1h.x + hf[5] * a1h.y + hf[6] * a1h.z + hf[7] * a1h.w;
    float s2 = hf[0] * a2l.x + hf[1] * a2l.y + hf[2] * a2l.z + hf[3] * a2l.w
             + hf[4] * a2h.x + hf[5] * a2h.y + hf[6] * a2h.z + hf[7] * a2h.w;
#pragma unroll
    for (int o = 32; o > 0; o >>= 1) {
        s1 += __shfl_xor(s1, o);
        s2 += __shfl_xor(s2, o);
    }
    if (lane == 0) {
        f1[row]  = s1;
        f2s[row] = s2 + b2[0];
    }
}

// ---------------- K4: fused masked-softmax attention @ h (partials) --------
// grid 512 = 128 bands x 4 j-splits -> 2 blocks/CU resident (16 waves/CU),
// so one block's phase1 HBM adj stream overlaps the other's phase2 MFMA.
// js = blockIdx&3: with round-robin XCD dispatch each XCD touches one 2MB
// HT2 j-slice (fits per-XCD L2). 512 thr / 8 waves; wave tile 64r x 64c.
// Per 128-j chunk: phase1 (16 weights/thread from prefetched regs -> LDS),
// one barrier, prefetch next chunk's adj/f2 regs, 4 barrier-free k-steps.
__launch_bounds__(512, 4)
__global__ void k_attn(const int* __restrict__ adj,    // [8192][8192]
                       const short* __restrict__ HT2,  // [256][512][32]
                       const float* __restrict__ f1,
                       const float* __restrict__ f2s,
                       float* __restrict__ nump,       // [4][8192][512]
                       float* __restrict__ denomp)     // [4][8192]
{
    __shared__ __align__(16) short wt[2][BM * BKC];    // 32 KB

    const int t    = threadIdx.x;
    const int lane = t & 63;
    const int w    = t >> 6;          // 0..7 col group (64 cols)
    const int m    = lane & 15;
    const int q    = lane >> 4;

    const int js   = blockIdx.x & 3;
    const int band = blockIdx.x >> 2; // 0..127
    const int r0   = band * BM;
    const int jb0  = js * 2048;

    // producer: 1 row x 16 j per thread (64 rows x 8 groups)
    const int prow = t >> 3;          // 0..63
    const int jg   = t & 7;           // 16-j group within 128-chunk

    const float f1v = f1[r0 + prow];
    const int*   adjp = adj + (size_t)(r0 + prow) * NR + jb0 + jg * 16;
    const float* f2p  = f2s + jb0 + jg * 16;

    f32x4 acc[4][4] = {};
    float dsum = 0.f;

    // prologue: prefetch chunk 0
    int4   aj[4];
    float4 fv[4];
#pragma unroll
    for (int g = 0; g < 4; ++g) {
        aj[g] = ((const int4*)adjp)[g];
        fv[g] = ((const float4*)f2p)[g];
    }

#pragma unroll 1
    for (int ch = 0; ch < 2048 / BKC; ++ch) {
        const int p = ch & 1;
        // ---- phase 1: 16 weights from prefetched regs ----
        float wgt[16];
#pragma unroll
        for (int jj = 0; jj < 16; ++jj) {
            int   a  = ((const int*)aj)[jj];
            float s  = f1v + ((const float*)fv)[jj];
            float l  = fmaxf(s, 0.2f * s);
            float e  = __expf(l);
            float wv = (a != 0) ? e : 0.f;
            dsum += wv;
            wgt[jj] = wv;
        }
        s8v wv0, wv1;
#pragma unroll
        for (int jj = 0; jj < 8; ++jj) {
            wv0[jj] = bf16_rtne(wgt[jj]);
            wv1[jj] = bf16_rtne(wgt[8 + jj]);
        }
        const int sw = prow & 15;
        *(s8v*)&wt[p][prow * BKC + (((2 * jg) ^ sw) << 3)]     = wv0;
        *(s8v*)&wt[p][prow * BKC + (((2 * jg + 1) ^ sw) << 3)] = wv1;

        __syncthreads();

        // ---- prefetch next chunk (issued before MFMAs; overlaps them) ----
        const int chn = (ch + 1) & (2048 / BKC - 1);   // wraps on last (dummy)
#pragma unroll
        for (int g = 0; g < 4; ++g) {
            aj[g] = ((const int4*)(adjp + chn * BKC))[g];
            fv[g] = ((const float4*)(f2p + chn * BKC))[g];
        }

        // ---- phase 2: 4 barrier-free k-steps ----
#pragma unroll
        for (int kk = 0; kk < 4; ++kk) {
            const int jt = (jb0 + ch * BKC + kk * 32) >> 5;
            const short* hb = HT2 + (size_t)jt * 16384 + q * 8;
            s8v af[4];
#pragma unroll
            for (int i = 0; i < 4; ++i) {
                int row = i * 16 + m;
                af[i] = *(const s8v*)&wt[p][row * BKC + (((kk * 4 + q) ^ m) << 3)];
            }
#pragma unroll
            for (int nt = 0; nt < 4; ++nt) {
                s8v b = *(const s8v*)(hb + (size_t)(w * 64 + nt * 16 + m) * 32);
#pragma unroll
                for (int i = 0; i < 4; ++i)
                    acc[i][nt] = __builtin_amdgcn_mfma_f32_16x16x32_bf16(af[i], b, acc[i][nt], 0, 0, 0);
            }
        }
    }

    // ---- partial denominators: reduce over the 8 producer threads per row
    dsum += __shfl_xor(dsum, 1);
    dsum += __shfl_xor(dsum, 2);
    dsum += __shfl_xor(dsum, 4);
    if (jg == 0) denomp[(size_t)js * NR + r0 + prow] = dsum;

    // ---- partial numerators
    float* np = nump + (size_t)js * NR * FD;
#pragma unroll
    for (int i = 0; i < 4; ++i)
#pragma unroll
        for (int nt = 0; nt < 4; ++nt)
#pragma unroll
            for (int r = 0; r < 4; ++r) {
                int row = r0 + i * 16 + q * 4 + r;
                int col = w * 64 + nt * 16 + m;
                np[(size_t)row * FD + col] = acc[i][nt][r];
            }
}

// ---------------- K5: combine j-split partials, softmax divide, ELU --------
__global__ void k_combine(const float* __restrict__ nump,
                          const float* __restrict__ denomp,
                          float* __restrict__ out)
{
    size_t e = ((size_t)blockIdx.x * 256 + threadIdx.x) * 4;
    int row = (int)(e >> 9);
    float4 n0 = *(const float4*)(nump + e);
    float4 n1 = *(const float4*)(nump + (size_t)NR * FD + e);
    float4 n2 = *(const float4*)(nump + (size_t)2 * NR * FD + e);
    float4 n3 = *(const float4*)(nump + (size_t)3 * NR * FD + e);
    float d = denomp[row] + denomp[NR + row] + denomp[2 * NR + row] + denomp[3 * NR + row];
    float inv = 1.0f / d;
    float4 o;
    o.x = (n0.x + n1.x + n2.x + n3.x) * inv;
    o.y = (n0.y + n1.y + n2.y + n3.y) * inv;
    o.z = (n0.z + n1.z + n2.z + n3.z) * inv;
    o.w = (n0.w + n1.w + n2.w + n3.w) * inv;
    o.x = (o.x > 0.f) ? o.x : (__expf(o.x) - 1.f);
    o.y = (o.y > 0.f) ? o.y : (__expf(o.y) - 1.f);
    o.z = (o.z > 0.f) ? o.z : (__expf(o.z) - 1.f);
    o.w = (o.w > 0.f) ? o.w : (__expf(o.w) - 1.f);
    *(float4*)(out + e) = o;
}

extern "C" void kernel_launch(void* const* d_in, const int* in_sizes, int n_in,
                              void* d_out, int out_size, void* d_ws, size_t ws_size,
                              hipStream_t stream) {
    const float* inp = (const float*)d_in[0];
    const int*   adj = (const int*)d_in[1];
    const float* W1  = (const float*)d_in[2];
    const float* b1  = (const float*)d_in[3];
    const float* a1  = (const float*)d_in[4];
    const float* a2  = (const float*)d_in[5];
    const float* b2  = (const float*)d_in[6];
    float* out = (float*)d_out;

    // workspace layout
    short* inp_bf = (short*)d_ws;                        // 8 MB
    short* w1t    = inp_bf + (size_t)NR * FD;            // 0.5 MB
    short* h      = w1t + (size_t)FD * FD;               // 8 MB
    short* ht2    = h + (size_t)NR * FD;                 // 8 MB
    float* f1     = (float*)(ht2 + (size_t)FD * NR);     // 32 KB
    float* f2s    = f1 + NR;                             // 32 KB
    float* nump   = f2s + NR;                            // 64 MB
    float* denomp = nump + (size_t)4 * NR * FD;          // 128 KB

    k_convert<<<(NR * FD / 4) / 256, 256, 0, stream>>>(inp, inp_bf);
    k_w1t<<<(FD * FD) / 256, 256, 0, stream>>>(W1, w1t);
    dim3 g1(NR / 32, FD / 128);
    k_gemm_h<<<g1, 256, 0, stream>>>(inp_bf, w1t, b1, h, ht2);
    k_f1f2<<<NR / 4, 256, 0, stream>>>(h, a1, a2, b2, f1, f2s);
    k_attn<<<128 * 4, 512, 0, stream>>>(adj, ht2, f1, f2s, nump, denomp);
    k_combine<<<(NR * FD / 4) / 256, 256, 0, stream>>>(nump, denomp, out);
}